// Round 4
// baseline (236.350 us; speedup 1.0000x reference)
//
#include <hip/hip_runtime.h>

// Parametric LIF forward (spike output only).
// x: [B=64, T=64, N=8192] fp32.  out: same shape, values in {0,1}.
// Recurrence per (b,n):  u = last*sig + x[t];  s = (u >= th);
//                        last = (u + lamb*(u-last)) * (1-s)
//
// R3 post-mortem: float2 variant = 16 waves/CU; prefetch distance (1 stage
// ~224 cyc/wave x 4 waves/SIMD ~ 896 cyc) barely covers 900-cyc HBM latency
// -> ~50% BW efficiency. R4: one scalar float per thread -> 2048 WGs,
// 8 blocks/CU = 32 waves/CU (8/SIMD, 100% occupancy); power-of-2 N makes
// b/n a shift/mask. 8-deep register double-buffered prefetch retained.
// All FP ops via *_rn intrinsics: forbid FMA contraction, match numpy bitwise
// (output is {0,1}; any spike flip = absmax 1.0).

#define LIF_B 64
#define LIF_T 64
#define LIF_N 8192
#define UN 8              // t-steps per pipeline stage
#define NSTAGE (LIF_T / UN)

__global__ __launch_bounds__(256, 8) void lif_fwd_kernel(
    const float* __restrict__ x,
    const float* __restrict__ tau_p,
    const float* __restrict__ lamb_p,
    const float* __restrict__ th_p,
    float* __restrict__ out)
{
    const int tid = blockIdx.x * blockDim.x + threadIdx.x;   // 0 .. B*N-1
    const int b   = tid >> 13;                               // tid / 8192
    const int n   = tid & (LIF_N - 1);

    const float sig  = 1.0f / (1.0f + expf(-tau_p[0]));      // 0.5 exact for tau_p=0
    const float lamb = lamb_p[0];
    const float th   = th_p[0];

    float last = 0.0f;
    const size_t base = (size_t)b * LIF_T * LIF_N + n;

    float cur[UN], nxt[UN];

#pragma unroll
    for (int i = 0; i < UN; ++i)
        cur[i] = x[base + (size_t)i * LIF_N];

#pragma unroll
    for (int k = 0; k < NSTAGE; ++k) {
        // Prefetch stage k+1 before touching stage k.
        if (k + 1 < NSTAGE) {
#pragma unroll
            for (int i = 0; i < UN; ++i)
                nxt[i] = x[base + (size_t)((k + 1) * UN + i) * LIF_N];
        }

#pragma unroll
        for (int i = 0; i < UN; ++i) {
            float u = __fadd_rn(__fmul_rn(last, sig), cur[i]);
            float s = (u >= th) ? 1.0f : 0.0f;
            last = __fmul_rn(__fadd_rn(u, __fmul_rn(lamb, __fsub_rn(u, last))),
                             __fsub_rn(1.0f, s));
            __builtin_nontemporal_store(s, &out[base + (size_t)(k * UN + i) * LIF_N]);
        }

#pragma unroll
        for (int i = 0; i < UN; ++i)
            cur[i] = nxt[i];
    }
}

extern "C" void kernel_launch(void* const* d_in, const int* in_sizes, int n_in,
                              void* d_out, int out_size, void* d_ws, size_t ws_size,
                              hipStream_t stream) {
    (void)in_sizes; (void)n_in; (void)out_size; (void)d_ws; (void)ws_size;

    const float* x     = (const float*)d_in[0];
    const float* tau_p = (const float*)d_in[1];
    const float* lamb  = (const float*)d_in[2];
    const float* th    = (const float*)d_in[3];
    float*       out   = (float*)d_out;

    const int total_threads = LIF_B * LIF_N;         // 524288
    const int block = 256;
    const int grid  = total_threads / block;         // 2048

    lif_fwd_kernel<<<grid, block, 0, stream>>>(x, tau_p, lamb, th, out);
}